// Round 1
// baseline (285.104 us; speedup 1.0000x reference)
//
#include <hip/hip_runtime.h>
#include <hip/hip_bf16.h>
#include <math.h>

#define SEQ 2048
#define DM 256
#define NH 8
#define DH 32

// ---------------- projection: out[s,c] = sum_d in[s,d] * W[c,d] ----------------
// 8 rows per block, 256 threads (one output column per thread).
__global__ __launch_bounds__(256) void proj2_kernel(
    const float* __restrict__ x, const float* __restrict__ Wa,
    const float* __restrict__ Wb, float* __restrict__ outA, float* __restrict__ outB)
{
    __shared__ float xs[8 * DM];
    const int tid = threadIdx.x;
    const int rb = blockIdx.x * 8;
    for (int i = tid; i < 8 * DM; i += 256) xs[i] = x[rb * DM + i];
    __syncthreads();

    const int c = tid;
    float accA[8] = {0,0,0,0,0,0,0,0};
    float accB[8] = {0,0,0,0,0,0,0,0};
    const float4* wa = (const float4*)(Wa + c * DM);
    const float4* wb = (const float4*)(Wb + c * DM);
    for (int k4 = 0; k4 < DM / 4; ++k4) {
        float4 a = wa[k4];
        float4 b = wb[k4];
        #pragma unroll
        for (int r = 0; r < 8; ++r) {
            float4 xv = *(const float4*)&xs[r * DM + k4 * 4];
            accA[r] += xv.x * a.x + xv.y * a.y + xv.z * a.z + xv.w * a.w;
            accB[r] += xv.x * b.x + xv.y * b.y + xv.z * b.z + xv.w * b.w;
        }
    }
    #pragma unroll
    for (int r = 0; r < 8; ++r) {
        outA[(rb + r) * DM + c] = accA[r];
        outB[(rb + r) * DM + c] = accB[r];
    }
}

__global__ __launch_bounds__(256) void proj1_kernel(
    const float* __restrict__ x, const float* __restrict__ Wa, float* __restrict__ outA)
{
    __shared__ float xs[8 * DM];
    const int tid = threadIdx.x;
    const int rb = blockIdx.x * 8;
    for (int i = tid; i < 8 * DM; i += 256) xs[i] = x[rb * DM + i];
    __syncthreads();

    const int c = tid;
    float accA[8] = {0,0,0,0,0,0,0,0};
    const float4* wa = (const float4*)(Wa + c * DM);
    for (int k4 = 0; k4 < DM / 4; ++k4) {
        float4 a = wa[k4];
        #pragma unroll
        for (int r = 0; r < 8; ++r) {
            float4 xv = *(const float4*)&xs[r * DM + k4 * 4];
            accA[r] += xv.x * a.x + xv.y * a.y + xv.z * a.z + xv.w * a.w;
        }
    }
    #pragma unroll
    for (int r = 0; r < 8; ++r) outA[(rb + r) * DM + c] = accA[r];
}

// ---------------- RoPE over full 256-dim rows, with token_positions gather ----------------
// out[s, :] = rope(XQ[p, :], angle base p), p = tp[s]
__global__ __launch_bounds__(256) void rope_kernel(
    const float* __restrict__ XQ, const int* __restrict__ tp, float* __restrict__ Q)
{
    const int s = blockIdx.x;
    const int t = threadIdx.x;
    const int p = tp[s];
    const int c = t >> 1;
    // inv = 10000^(-2c/256) = exp2(-c * log2(10000)/128)
    const float kf = 0.10381025296522976f; // log2(10000)/128
    float ang = (float)p * exp2f(-(float)c * kf);
    float sn, cs;
    sincosf(ang, &sn, &cs);
    float xe = XQ[p * DM + 2 * c];
    float xo = XQ[p * DM + 2 * c + 1];
    float out = (t & 1) ? (xe * sn + xo * cs) : (xe * cs - xo * sn);
    Q[s * DM + t] = out;
}

// ---------------- attention (anti-causal mask: keep j > i, else -1e9) ----------------
// grid: NH * (SEQ/64) blocks, 512 threads.
// thread t: split = t>>6 (key range), r = t&63 (query row in block).
#define ROWS 64
#define SPLIT 8
#define KEYS_PER_SPLIT (SEQ / SPLIT)

__global__ __launch_bounds__(512) void attn_kernel(
    const float* __restrict__ Q, const float* __restrict__ K,
    const float* __restrict__ V, float* __restrict__ O)
{
    __shared__ float sm[SPLIT][ROWS];
    __shared__ float sl[SPLIT][ROWS];
    __shared__ float sscale[SPLIT][ROWS];
    __shared__ float sinvl[ROWS];
    __shared__ float sacc[SPLIT][ROWS][DH + 1]; // +1 pad: kill stride-32 bank conflict

    const int t = threadIdx.x;
    const int split = t >> 6;
    const int r = t & 63;
    const int head = blockIdx.x >> 5;
    const int rb = (blockIdx.x & 31) << 6;
    const int row = rb + r;

    float q[DH];
    const float4* qp4 = (const float4*)(Q + row * DM + head * DH);
    #pragma unroll
    for (int i = 0; i < DH / 4; ++i) {
        float4 v4 = qp4[i];
        q[4 * i + 0] = v4.x; q[4 * i + 1] = v4.y; q[4 * i + 2] = v4.z; q[4 * i + 3] = v4.w;
    }

    float m = -INFINITY, l = 0.f;
    float acc[DH];
    #pragma unroll
    for (int i = 0; i < DH; ++i) acc[i] = 0.f;

    const int j0 = split * KEYS_PER_SPLIT;
    for (int j = j0; j < j0 + KEYS_PER_SPLIT; ++j) {
        const float4* kp4 = (const float4*)(K + j * DM + head * DH);
        float s = 0.f;
        #pragma unroll
        for (int i = 0; i < DH / 4; ++i) {
            float4 kv = kp4[i];
            s += q[4 * i] * kv.x + q[4 * i + 1] * kv.y + q[4 * i + 2] * kv.z + q[4 * i + 3] * kv.w;
        }
        s *= 0.17677669529663687f; // 1/sqrt(32)
        s = (j > row) ? s : -1.0e9f; // anti-causal: keep strictly-future only
        if (s > m) {
            float corr = __expf(m - s);
            m = s;
            l *= corr;
            #pragma unroll
            for (int i = 0; i < DH; ++i) acc[i] *= corr;
        }
        float w = __expf(s - m);
        l += w;
        const float4* vp4 = (const float4*)(V + j * DM + head * DH);
        #pragma unroll
        for (int i = 0; i < DH / 4; ++i) {
            float4 vv = vp4[i];
            acc[4 * i + 0] += w * vv.x;
            acc[4 * i + 1] += w * vv.y;
            acc[4 * i + 2] += w * vv.z;
            acc[4 * i + 3] += w * vv.w;
        }
    }

    sm[split][r] = m;
    sl[split][r] = l;
    #pragma unroll
    for (int i = 0; i < DH; ++i) sacc[split][r][i] = acc[i];
    __syncthreads();

    if (t < ROWS) {
        float mx = sm[0][t];
        #pragma unroll
        for (int sp = 1; sp < SPLIT; ++sp) mx = fmaxf(mx, sm[sp][t]);
        float ltot = 0.f;
        #pragma unroll
        for (int sp = 0; sp < SPLIT; ++sp) {
            float sc = __expf(sm[sp][t] - mx);
            sscale[sp][t] = sc;
            ltot += sl[sp][t] * sc;
        }
        sinvl[t] = 1.0f / ltot;
    }
    __syncthreads();

    {
        const int rr = t >> 3;
        const int cg = (t & 7) * 4;
        #pragma unroll
        for (int cc = 0; cc < 4; ++cc) {
            int c = cg + cc;
            float o = 0.f;
            #pragma unroll
            for (int sp = 0; sp < SPLIT; ++sp) o += sacc[sp][rr][c] * sscale[sp][rr];
            O[(rb + rr) * DM + head * DH + c] = o * sinvl[rr];
        }
    }
}

extern "C" void kernel_launch(void* const* d_in, const int* in_sizes, int n_in,
                              void* d_out, int out_size, void* d_ws, size_t ws_size,
                              hipStream_t stream) {
    const float* x  = (const float*)d_in[0];
    const int*   tp = (const int*)d_in[1];
    const float* Wq = (const float*)d_in[2];
    const float* Wk = (const float*)d_in[3];
    // d_in[4] = v_weight — UNUSED: reference computes x_v with q_weight (bug replicated)
    const float* Wo = (const float*)d_in[5];
    float* out = (float*)d_out;

    float* ws = (float*)d_ws;
    float* XQ = ws;                 // 2048*256 (also serves as V, pre-RoPE)
    float* XK = ws + SEQ * DM;      // 2048*256
    float* Qr = ws + 2 * SEQ * DM;  // roped Q
    float* AO = ws + 3 * SEQ * DM;  // attention output (head-concat layout)

    proj2_kernel<<<SEQ / 8, 256, 0, stream>>>(x, Wq, Wk, XQ, XK);
    rope_kernel<<<SEQ, 256, 0, stream>>>(XQ, tp, Qr);
    attn_kernel<<<NH * (SEQ / 64), 512, 0, stream>>>(Qr, XK, XQ, AO);
    proj1_kernel<<<SEQ / 8, 256, 0, stream>>>(AO, Wo, out);
}

// Round 2
// 81.078 us; speedup vs baseline: 3.5164x; 3.5164x over previous
//
#include <hip/hip_runtime.h>
#include <hip/hip_bf16.h>
#include <math.h>

#define SEQ 2048
#define DM 256
#define NH 8
#define DH 32

typedef unsigned short ushort_t;
typedef __attribute__((ext_vector_type(8))) unsigned short u16x8;
typedef __attribute__((ext_vector_type(8))) __bf16 b16x8;
typedef __attribute__((ext_vector_type(4))) float f32x4;

static __device__ __forceinline__ b16x8 as_b(u16x8 v) {
    union { u16x8 u; b16x8 b; } x; x.u = v; return x.b;
}
static __device__ __forceinline__ ushort_t f2b(float f) {
    unsigned u = __float_as_uint(f);
    return (ushort_t)((u + 0x7fffu + ((u >> 16) & 1u)) >> 16);
}

// ---------------- proj2: XQ(f32) = x*Wq^T ; Kb(bf16) = x*Wk^T ; Vt(bf16, transposed+pi) ; psum ----------------
__global__ __launch_bounds__(256) void proj2_kernel(
    const float* __restrict__ x, const float* __restrict__ Wa, const float* __restrict__ Wb,
    float* __restrict__ XQ, ushort_t* __restrict__ Kb, ushort_t* __restrict__ Vtg,
    float* __restrict__ psum)
{
    __shared__ float xs[8 * DM];
    const int tid = threadIdx.x;
    const int rb = blockIdx.x * 8;
    for (int i = tid; i < 8 * DM; i += 256) xs[i] = x[rb * DM + i];
    __syncthreads();

    const int c = tid;
    float accA[8] = {0,0,0,0,0,0,0,0};
    float accB[8] = {0,0,0,0,0,0,0,0};
    const float4* wa = (const float4*)(Wa + c * DM);
    const float4* wb = (const float4*)(Wb + c * DM);
    for (int k4 = 0; k4 < DM / 4; ++k4) {
        float4 a = wa[k4];
        float4 b = wb[k4];
        #pragma unroll
        for (int r = 0; r < 8; ++r) {
            float4 xv = *(const float4*)&xs[r * DM + k4 * 4];
            accA[r] += xv.x * a.x + xv.y * a.y + xv.z * a.z + xv.w * a.w;
            accB[r] += xv.x * b.x + xv.y * b.y + xv.z * b.z + xv.w * b.w;
        }
    }
    float ps = 0.f;
    const int vbase = c * SEQ + (rb & ~31);
    #pragma unroll
    for (int r = 0; r < 8; ++r) {
        XQ[(rb + r) * DM + c] = accA[r];
        Kb[(rb + r) * DM + c] = f2b(accB[r]);
        int kl = (rb + r) & 31;
        int pos = ((kl >> 2) & 3) * 8 + ((kl >> 4) & 1) * 4 + (kl & 3);
        Vtg[vbase + pos] = f2b(accA[r]);   // V = XQ (reference uses q_weight for V)
        ps += accA[r];
    }
    psum[blockIdx.x * 256 + c] = ps;
}

// ---------------- RoPE (full 256-dim rows, token_positions gather) -> Qb bf16 ----------------
__global__ __launch_bounds__(256) void rope_kernel(
    const float* __restrict__ XQ, const int* __restrict__ tp, ushort_t* __restrict__ Qb)
{
    const int s = blockIdx.x;
    const int t = threadIdx.x;
    const int p = tp[s];
    const int c = t >> 1;
    const float kf = 0.10381025296522976f; // log2(10000)/128
    float ang = (float)p * exp2f(-(float)c * kf);
    float sn, cs;
    sincosf(ang, &sn, &cs);
    float xe = XQ[p * DM + 2 * c];
    float xo = XQ[p * DM + 2 * c + 1];
    float out = (t & 1) ? (xe * sn + xo * cs) : (xe * cs - xo * sn);
    Qb[s * DM + t] = f2b(out);
}

// ---------------- fix row 2047: fully-masked softmax -> uniform mean of V ----------------
__global__ __launch_bounds__(256) void fix_kernel(const float* __restrict__ psum, float* __restrict__ AO)
{
    const int c = threadIdx.x;
    float s = 0.f;
    for (int b = 0; b < 256; ++b) s += psum[b * 256 + c];
    AO[2047 * DM + c] = s * (1.0f / 2048.0f);
}

// ---------------- MFMA flash attention (anti-causal), no LDS ----------------
// grid (32, 8): pair index p -> waves 0,1 handle qt32=p; waves 2,3 handle qt32=63-p.
// Each wave: 16 q rows. S^T = mfma(K, Q^T); lane owns one q column.
__global__ __launch_bounds__(256) void attn_kernel(
    const ushort_t* __restrict__ Qb, const ushort_t* __restrict__ Kb,
    const ushort_t* __restrict__ Vt, float* __restrict__ AO)
{
    const int t = threadIdx.x;
    const int w = t >> 6;
    const int l = t & 63;
    const int g = l >> 4;
    const int ln = l & 15;
    const int h = blockIdx.y;
    const int p = blockIdx.x;
    const int qt32 = (w < 2) ? p : (63 - p);
    const int qbase = qt32 * 32 + (w & 1) * 16;
    const int qrow = qbase + ln;

    // persistent Q B-fragment: Qb[qrow][h*32 + 8g + j]
    const u16x8 qf = *(const u16x8*)(Qb + qrow * DM + h * DH + g * 8);

    int kt_lo = qt32 >> 1;
    if (qt32 == 63) kt_lo = 31;   // rows 2016..2046 only need tile 31; row 2047 handled by fix_kernel

    const ushort_t* Kh = Kb + h * DH;
    const ushort_t* Vh = Vt + (h * DH) * SEQ;

    float m = -INFINITY, lsum = 0.f;
    f32x4 acc0 = {0,0,0,0}, acc1 = {0,0,0,0};

    u16x8 ka[4], va[4], kn[4], vn[4];
    #pragma unroll
    for (int st = 0; st < 4; ++st)
        ka[st] = *(const u16x8*)(Kh + (kt_lo * 64 + st * 16 + ln) * DM + g * 8);
    #pragma unroll
    for (int c = 0; c < 2; ++c)
        #pragma unroll
        for (int df = 0; df < 2; ++df)
            va[c * 2 + df] = *(const u16x8*)(Vh + (df * 16 + ln) * SEQ + kt_lo * 64 + c * 32 + g * 8);

    for (int kt = kt_lo; kt < 32; ++kt) {
        if (kt < 31) {
            #pragma unroll
            for (int st = 0; st < 4; ++st)
                kn[st] = *(const u16x8*)(Kh + ((kt + 1) * 64 + st * 16 + ln) * DM + g * 8);
            #pragma unroll
            for (int c = 0; c < 2; ++c)
                #pragma unroll
                for (int df = 0; df < 2; ++df)
                    vn[c * 2 + df] = *(const u16x8*)(Vh + (df * 16 + ln) * SEQ + (kt + 1) * 64 + c * 32 + g * 8);
        }

        // S^T[k][q] for 4 sub-tiles of 16 keys
        f32x4 s[4];
        #pragma unroll
        for (int st = 0; st < 4; ++st) {
            f32x4 z = {0,0,0,0};
            s[st] = __builtin_amdgcn_mfma_f32_16x16x32_bf16(as_b(ka[st]), as_b(qf), z, 0, 0, 0);
        }

        float sv[16];
        float tmax = -INFINITY;
        #pragma unroll
        for (int st = 0; st < 4; ++st)
            #pragma unroll
            for (int r = 0; r < 4; ++r) {
                int kg = kt * 64 + st * 16 + g * 4 + r;
                float v = s[st][r] * 0.17677669529663687f; // 1/sqrt(32)
                v = (kg > qrow) ? v : -1.0e9f;             // anti-causal mask
                sv[st * 4 + r] = v;
                tmax = fmaxf(tmax, v);
            }
        tmax = fmaxf(tmax, __shfl_xor(tmax, 16, 64));
        tmax = fmaxf(tmax, __shfl_xor(tmax, 32, 64));

        float mn = fmaxf(m, tmax);
        float corr = __expf(m - mn);
        m = mn;

        float ts = 0.f;
        ushort_t pb[16];
        #pragma unroll
        for (int i = 0; i < 16; ++i) {
            float e = __expf(sv[i] - m);
            ts += e;
            pb[i] = f2b(e);
        }
        ts += __shfl_xor(ts, 16, 64);
        ts += __shfl_xor(ts, 32, 64);
        lsum = lsum * corr + ts;
        #pragma unroll
        for (int i = 0; i < 4; ++i) { acc0[i] *= corr; acc1[i] *= corr; }

        // PV: chunk c uses P sub-tiles 2c, 2c+1 (pi-order matches Vt layout)
        #pragma unroll
        for (int c = 0; c < 2; ++c) {
            u16x8 pf;
            #pragma unroll
            for (int r = 0; r < 4; ++r) { pf[r] = pb[(2 * c) * 4 + r]; pf[4 + r] = pb[(2 * c + 1) * 4 + r]; }
            acc0 = __builtin_amdgcn_mfma_f32_16x16x32_bf16(as_b(va[c * 2 + 0]), as_b(pf), acc0, 0, 0, 0);
            acc1 = __builtin_amdgcn_mfma_f32_16x16x32_bf16(as_b(va[c * 2 + 1]), as_b(pf), acc1, 0, 0, 0);
        }

        #pragma unroll
        for (int i = 0; i < 4; ++i) { ka[i] = kn[i]; va[i] = vn[i]; }
    }

    if (qrow != 2047) {
        float inv = 1.0f / lsum;
        float* o = AO + qrow * DM + h * DH;
        #pragma unroll
        for (int r = 0; r < 4; ++r) {
            o[4 * g + r]      = acc0[r] * inv;
            o[16 + 4 * g + r] = acc1[r] * inv;
        }
    }
}

// ---------------- output projection (fp32) ----------------
__global__ __launch_bounds__(256) void proj1_kernel(
    const float* __restrict__ x, const float* __restrict__ Wa, float* __restrict__ outA)
{
    __shared__ float xs[8 * DM];
    const int tid = threadIdx.x;
    const int rb = blockIdx.x * 8;
    for (int i = tid; i < 8 * DM; i += 256) xs[i] = x[rb * DM + i];
    __syncthreads();

    const int c = tid;
    float accA[8] = {0,0,0,0,0,0,0,0};
    const float4* wa = (const float4*)(Wa + c * DM);
    for (int k4 = 0; k4 < DM / 4; ++k4) {
        float4 a = wa[k4];
        #pragma unroll
        for (int r = 0; r < 8; ++r) {
            float4 xv = *(const float4*)&xs[r * DM + k4 * 4];
            accA[r] += xv.x * a.x + xv.y * a.y + xv.z * a.z + xv.w * a.w;
        }
    }
    #pragma unroll
    for (int r = 0; r < 8; ++r) outA[(rb + r) * DM + c] = accA[r];
}

extern "C" void kernel_launch(void* const* d_in, const int* in_sizes, int n_in,
                              void* d_out, int out_size, void* d_ws, size_t ws_size,
                              hipStream_t stream) {
    const float* x  = (const float*)d_in[0];
    const int*   tp = (const int*)d_in[1];
    const float* Wq = (const float*)d_in[2];
    const float* Wk = (const float*)d_in[3];
    // d_in[4] = v_weight — UNUSED (reference computes x_v with q_weight)
    const float* Wo = (const float*)d_in[5];
    float* out = (float*)d_out;

    float* ws = (float*)d_ws;
    float*    XQ   = ws;                         // 2048*256 f32  (= V, pre-RoPE)
    float*    AO   = ws + 524288;                // 2048*256 f32
    float*    psum = ws + 1048576;               // 256*256 f32
    ushort_t* Qb   = (ushort_t*)(ws + 1114112);  // 2048*256 bf16
    ushort_t* Kb   = (ushort_t*)(ws + 1376256);  // 2048*256 bf16
    ushort_t* Vt   = (ushort_t*)(ws + 1638400);  // [256 c][2048 kpos] bf16, pi-permuted

    proj2_kernel<<<SEQ / 8, 256, 0, stream>>>(x, Wq, Wk, XQ, Kb, Vt, psum);
    rope_kernel<<<SEQ, 256, 0, stream>>>(XQ, tp, Qb);
    fix_kernel<<<1, 256, 0, stream>>>(psum, AO);
    attn_kernel<<<dim3(32, NH), 256, 0, stream>>>(Qb, Kb, Vt, AO);
    proj1_kernel<<<SEQ / 8, 256, 0, stream>>>(AO, Wo, out);
}

// Round 3
// 51.555 us; speedup vs baseline: 5.5301x; 1.5727x over previous
//
#include <hip/hip_runtime.h>
#include <hip/hip_bf16.h>
#include <math.h>

#define SEQ 2048
#define DM 256
#define NH 8
#define DH 32

typedef unsigned short ushort_t;
typedef __attribute__((ext_vector_type(8))) unsigned short u16x8;
typedef __attribute__((ext_vector_type(8))) __bf16 b16x8;
typedef __attribute__((ext_vector_type(4))) float f32x4;

static __device__ __forceinline__ b16x8 as_b(u16x8 v) {
    union { u16x8 u; b16x8 b; } x; x.u = v; return x.b;
}
// RTN-even f32 -> bf16 bits
static __device__ __forceinline__ ushort_t f2bh(float f) {
    unsigned u = __float_as_uint(f);
    return (ushort_t)((u + 0x7fffu + ((u >> 16) & 1u)) >> 16);
}

// ---------------- K1: convert x, [Wq;Wk], Wo to bf16 ----------------
// grid 352 x 256 threads, 8 elems/thread. 524288 + 131072 + 65536 = 720896 elems.
__global__ __launch_bounds__(256) void convert_kernel(
    const float* __restrict__ x, const float* __restrict__ Wq,
    const float* __restrict__ Wk, const float* __restrict__ Wo,
    ushort_t* __restrict__ Xbf, ushort_t* __restrict__ W2bf, ushort_t* __restrict__ Wobf)
{
    const int e = (blockIdx.x * 256 + threadIdx.x) * 8;
    const float* src;
    ushort_t* dst;
    if (e < 524288) { src = x + e; dst = Xbf + e; }
    else if (e < 655360) {
        int o = e - 524288;
        src = (o < 65536) ? (Wq + o) : (Wk + (o - 65536));
        dst = W2bf + o;
    } else {
        int o = e - 655360;
        src = Wo + o; dst = Wobf + o;
    }
    float4 a = ((const float4*)src)[0];
    float4 b = ((const float4*)src)[1];
    u16x8 r;
    r[0] = f2bh(a.x); r[1] = f2bh(a.y); r[2] = f2bh(a.z); r[3] = f2bh(a.w);
    r[4] = f2bh(b.x); r[5] = f2bh(b.y); r[6] = f2bh(b.z); r[7] = f2bh(b.w);
    *(u16x8*)dst = r;
}

// ---------------- K2: proj2 MFMA: C[2048x512] = Xbf * W2bf^T ----------------
// grid (32 mb, 8 nb), 256 thr = 4 waves x 16 rows. Register-resident, no LDS.
// nb<4: C cols are XQ (f32 out + Vt bf16 scatter + psum); nb>=4: Kbf bf16.
__global__ __launch_bounds__(256) void proj2_mfma(
    const ushort_t* __restrict__ Xbf, const ushort_t* __restrict__ W2bf,
    float* __restrict__ XQ, ushort_t* __restrict__ Kbf, ushort_t* __restrict__ Vt,
    float* __restrict__ psum)
{
    const int t = threadIdx.x;
    const int w = t >> 6, l = t & 63, g = l >> 4, ln = l & 15;
    const int mb = blockIdx.x, nb = blockIdx.y;
    const int row0 = mb * 64 + w * 16;
    const int col0 = nb * 64;

    u16x8 af[8];
    const ushort_t* ap = Xbf + (row0 + ln) * DM + g * 8;
    #pragma unroll
    for (int kk = 0; kk < 8; ++kk) af[kk] = *(const u16x8*)(ap + kk * 32);

    f32x4 acc[4] = {{0,0,0,0},{0,0,0,0},{0,0,0,0},{0,0,0,0}};
    #pragma unroll
    for (int kk = 0; kk < 8; ++kk) {
        #pragma unroll
        for (int nf = 0; nf < 4; ++nf) {
            u16x8 bfv = *(const u16x8*)(W2bf + (col0 + nf * 16 + ln) * DM + g * 8 + kk * 32);
            acc[nf] = __builtin_amdgcn_mfma_f32_16x16x32_bf16(as_b(af[kk]), as_b(bfv), acc[nf], 0, 0, 0);
        }
    }

    if (nb < 4) {
        #pragma unroll
        for (int nf = 0; nf < 4; ++nf) {
            const int col = col0 + nf * 16 + ln;
            #pragma unroll
            for (int r = 0; r < 4; ++r) {
                const int row = row0 + 4 * g + r;
                float v = acc[nf][r];
                XQ[row * DM + col] = v;
                int kl = row & 31;
                int pos = ((kl >> 2) & 3) * 8 + ((kl >> 4) & 1) * 4 + (kl & 3);
                Vt[col * SEQ + (row & ~31) + pos] = f2bh(v);
            }
            // column partial sum over this wave's 16 rows
            float s = acc[nf][0] + acc[nf][1] + acc[nf][2] + acc[nf][3];
            s += __shfl_xor(s, 16, 64);
            s += __shfl_xor(s, 32, 64);
            if (g == 0) psum[(mb * 4 + w) * DM + col] = s;
        }
    } else {
        #pragma unroll
        for (int nf = 0; nf < 4; ++nf) {
            const int col = col0 - 256 + nf * 16 + ln;
            #pragma unroll
            for (int r = 0; r < 4; ++r) {
                const int row = row0 + 4 * g + r;
                Kbf[row * DM + col] = f2bh(acc[nf][r]);
            }
        }
    }
}

// ---------------- K3: RoPE (full 256-dim rows, token_positions gather) ----------------
__global__ __launch_bounds__(256) void rope_kernel(
    const float* __restrict__ XQ, const int* __restrict__ tp, ushort_t* __restrict__ Qb)
{
    const int s = blockIdx.x;
    const int t = threadIdx.x;
    const int p = tp[s];
    const int c = t >> 1;
    const float kf = 0.10381025296522976f; // log2(10000)/128
    float ang = (float)p * exp2f(-(float)c * kf);
    float sn, cs;
    sincosf(ang, &sn, &cs);
    float xe = XQ[p * DM + 2 * c];
    float xo = XQ[p * DM + 2 * c + 1];
    float out = (t & 1) ? (xe * sn + xo * cs) : (xe * cs - xo * sn);
    Qb[s * DM + t] = f2bh(out);
}

// ---------------- K4: row 2047 = column mean of V (fully-masked softmax) ----------------
__global__ __launch_bounds__(256) void fix_kernel(const float* __restrict__ psum, ushort_t* __restrict__ AObf)
{
    const int c = threadIdx.x;
    float s = 0.f;
    for (int r = 0; r < 128; ++r) s += psum[r * DM + c];
    AObf[2047 * DM + c] = f2bh(s * (1.0f / 2048.0f));
}

// ---------------- K5: MFMA flash attention (anti-causal), 2-way k-split ----------------
// grid (64, 8), 256 thr. Waves 0,1: qt16=b halves 0,1; waves 2,3: qt16=127-b.
__global__ __launch_bounds__(256) void attn_kernel(
    const ushort_t* __restrict__ Qb, const ushort_t* __restrict__ Kb,
    const ushort_t* __restrict__ Vt, ushort_t* __restrict__ AObf)
{
    __shared__ float sm[4][64], sl[4][64], sacc[4][64][8];
    const int t = threadIdx.x;
    const int w = t >> 6, l = t & 63, g = l >> 4, ln = l & 15;
    const int h = blockIdx.y, b = blockIdx.x;
    const int qt16 = (w < 2) ? b : (127 - b);
    const int half = w & 1;
    const int qrow = qt16 * 16 + ln;
    const int kt_lo = qt16 >> 2;
    const int mid = (kt_lo + 33) >> 1;
    const int ks = half ? mid : kt_lo;
    const int ke = half ? 32 : mid;

    const u16x8 qf = *(const u16x8*)(Qb + qrow * DM + h * DH + g * 8);
    const ushort_t* Kh = Kb + h * DH;
    const ushort_t* Vh = Vt + (h * DH) * SEQ;

    float m = -INFINITY, lsum = 0.f;
    f32x4 acc0 = {0,0,0,0}, acc1 = {0,0,0,0};

    if (ks < ke) {
        u16x8 ka[4], va[4], kn[4], vn[4];
        #pragma unroll
        for (int st = 0; st < 4; ++st)
            ka[st] = *(const u16x8*)(Kh + (ks * 64 + st * 16 + ln) * DM + g * 8);
        #pragma unroll
        for (int c = 0; c < 2; ++c)
            #pragma unroll
            for (int df = 0; df < 2; ++df)
                va[c * 2 + df] = *(const u16x8*)(Vh + (df * 16 + ln) * SEQ + ks * 64 + c * 32 + g * 8);

        for (int kt = ks; kt < ke; ++kt) {
            if (kt + 1 < ke) {
                #pragma unroll
                for (int st = 0; st < 4; ++st)
                    kn[st] = *(const u16x8*)(Kh + ((kt + 1) * 64 + st * 16 + ln) * DM + g * 8);
                #pragma unroll
                for (int c = 0; c < 2; ++c)
                    #pragma unroll
                    for (int df = 0; df < 2; ++df)
                        vn[c * 2 + df] = *(const u16x8*)(Vh + (df * 16 + ln) * SEQ + (kt + 1) * 64 + c * 32 + g * 8);
            }

            f32x4 s[4];
            #pragma unroll
            for (int st = 0; st < 4; ++st) {
                f32x4 z = {0,0,0,0};
                s[st] = __builtin_amdgcn_mfma_f32_16x16x32_bf16(as_b(ka[st]), as_b(qf), z, 0, 0, 0);
            }

            float sv[16];
            float tmax = -INFINITY;
            #pragma unroll
            for (int st = 0; st < 4; ++st)
                #pragma unroll
                for (int r = 0; r < 4; ++r) {
                    int kg = kt * 64 + st * 16 + g * 4 + r;
                    float v = s[st][r] * 0.17677669529663687f; // 1/sqrt(32)
                    v = (kg > qrow) ? v : -1.0e9f;             // anti-causal mask
                    sv[st * 4 + r] = v;
                    tmax = fmaxf(tmax, v);
                }
            tmax = fmaxf(tmax, __shfl_xor(tmax, 16, 64));
            tmax = fmaxf(tmax, __shfl_xor(tmax, 32, 64));

            float mn = fmaxf(m, tmax);
            float corr = __expf(m - mn);
            m = mn;

            float ts = 0.f;
            ushort_t pb[16];
            #pragma unroll
            for (int i = 0; i < 16; ++i) {
                float e = __expf(sv[i] - m);
                ts += e;
                pb[i] = f2bh(e);
            }
            ts += __shfl_xor(ts, 16, 64);
            ts += __shfl_xor(ts, 32, 64);
            lsum = lsum * corr + ts;
            #pragma unroll
            for (int i = 0; i < 4; ++i) { acc0[i] *= corr; acc1[i] *= corr; }

            #pragma unroll
            for (int c = 0; c < 2; ++c) {
                u16x8 pf;
                #pragma unroll
                for (int r = 0; r < 4; ++r) { pf[r] = pb[(2 * c) * 4 + r]; pf[4 + r] = pb[(2 * c + 1) * 4 + r]; }
                acc0 = __builtin_amdgcn_mfma_f32_16x16x32_bf16(as_b(va[c * 2 + 0]), as_b(pf), acc0, 0, 0, 0);
                acc1 = __builtin_amdgcn_mfma_f32_16x16x32_bf16(as_b(va[c * 2 + 1]), as_b(pf), acc1, 0, 0, 0);
            }

            if (kt + 1 < ke) {
                #pragma unroll
                for (int i = 0; i < 4; ++i) { ka[i] = kn[i]; va[i] = vn[i]; }
            }
        }
    }

    sm[w][l] = m;
    sl[w][l] = lsum;
    #pragma unroll
    for (int r = 0; r < 4; ++r) { sacc[w][l][r] = acc0[r]; sacc[w][l][4 + r] = acc1[r]; }
    __syncthreads();

    if (half == 0 && qrow != 2047) {
        float mb_ = sm[w + 1][l], lb = sl[w + 1][l];
        float m2 = fmaxf(m, mb_);
        float ca = __expf(m - m2), cb = __expf(mb_ - m2);
        float inv = 1.0f / (lsum * ca + lb * cb);
        ushort_t* o = AObf + qrow * DM + h * DH;
        #pragma unroll
        for (int r = 0; r < 4; ++r) {
            float o0 = (acc0[r] * ca + sacc[w + 1][l][r] * cb) * inv;
            float o1 = (acc1[r] * ca + sacc[w + 1][l][4 + r] * cb) * inv;
            o[4 * g + r]      = f2bh(o0);
            o[16 + 4 * g + r] = f2bh(o1);
        }
    }
}

// ---------------- K6: proj1 MFMA: out[2048x256] = AObf * Wobf^T (f32 out) ----------------
// grid (32 mb, 8 nb), N-tile 32 (2 col frags).
__global__ __launch_bounds__(256) void proj1_mfma(
    const ushort_t* __restrict__ AObf, const ushort_t* __restrict__ Wobf,
    float* __restrict__ out)
{
    const int t = threadIdx.x;
    const int w = t >> 6, l = t & 63, g = l >> 4, ln = l & 15;
    const int mb = blockIdx.x, nb = blockIdx.y;
    const int row0 = mb * 64 + w * 16;
    const int col0 = nb * 32;

    u16x8 af[8];
    const ushort_t* ap = AObf + (row0 + ln) * DM + g * 8;
    #pragma unroll
    for (int kk = 0; kk < 8; ++kk) af[kk] = *(const u16x8*)(ap + kk * 32);

    f32x4 acc[2] = {{0,0,0,0},{0,0,0,0}};
    #pragma unroll
    for (int kk = 0; kk < 8; ++kk) {
        #pragma unroll
        for (int nf = 0; nf < 2; ++nf) {
            u16x8 bfv = *(const u16x8*)(Wobf + (col0 + nf * 16 + ln) * DM + g * 8 + kk * 32);
            acc[nf] = __builtin_amdgcn_mfma_f32_16x16x32_bf16(as_b(af[kk]), as_b(bfv), acc[nf], 0, 0, 0);
        }
    }
    #pragma unroll
    for (int nf = 0; nf < 2; ++nf) {
        const int col = col0 + nf * 16 + ln;
        #pragma unroll
        for (int r = 0; r < 4; ++r)
            out[(row0 + 4 * g + r) * DM + col] = acc[nf][r];
    }
}

extern "C" void kernel_launch(void* const* d_in, const int* in_sizes, int n_in,
                              void* d_out, int out_size, void* d_ws, size_t ws_size,
                              hipStream_t stream) {
    const float* x  = (const float*)d_in[0];
    const int*   tp = (const int*)d_in[1];
    const float* Wq = (const float*)d_in[2];
    const float* Wk = (const float*)d_in[3];
    // d_in[4] = v_weight — UNUSED (reference computes x_v with q_weight)
    const float* Wo = (const float*)d_in[5];
    float* out = (float*)d_out;

    float* ws = (float*)d_ws;
    float*    XQ   = ws;                          // 2048*256 f32 (= V pre-rope, f32)
    float*    psum = ws + 524288;                 // 128*256 f32
    ushort_t* Xbf  = (ushort_t*)(ws + 557056);    // 2048*256 bf16
    ushort_t* Kbf  = (ushort_t*)(ws + 819200);    // 2048*256 bf16
    ushort_t* Vt   = (ushort_t*)(ws + 1081344);   // [256][2048] bf16, pi-permuted
    ushort_t* Qb   = (ushort_t*)(ws + 1343488);   // 2048*256 bf16 (roped Q)
    ushort_t* AObf = (ushort_t*)(ws + 1605632);   // 2048*256 bf16
    ushort_t* W2bf = (ushort_t*)(ws + 1867776);   // 512*256 bf16
    ushort_t* Wobf = (ushort_t*)(ws + 1933312);   // 256*256 bf16

    convert_kernel<<<352, 256, 0, stream>>>(x, Wq, Wk, Wo, Xbf, W2bf, Wobf);
    proj2_mfma<<<dim3(32, 8), 256, 0, stream>>>(Xbf, W2bf, XQ, Kbf, Vt, psum);
    rope_kernel<<<SEQ, 256, 0, stream>>>(XQ, tp, Qb);
    fix_kernel<<<1, 256, 0, stream>>>(psum, AObf);
    attn_kernel<<<dim3(64, NH), 256, 0, stream>>>(Qb, Kbf, Vt, AObf);
    proj1_mfma<<<dim3(32, 8), 256, 0, stream>>>(AObf, Wobf, out);
}